// Round 12
// baseline (37.933 us; speedup 1.0000x reference)
//
#include <hip/hip_runtime.h>
#include <hip/hip_bf16.h>

#define TOKENS 16384
#define NEXP 8
#define INF 512
#define OUTF 512

#define BM 64
#define BN 128
#define BK 32
#define NST (INF / BK)     // 16 K-steps
#define MAXMT 40           // 2560 rows/expert; counts ~2048±42(σ) -> +12σ safe
#define EROWS (MAXMT * BM)

using f32x4 = __attribute__((ext_vector_type(4))) float;
using bfrag = __attribute__((ext_vector_type(8))) __bf16;
using s8v   = __attribute__((ext_vector_type(8))) short;

// fp32 -> bf16 RNE
__device__ __forceinline__ short f2bf(float f) {
  union { float f; unsigned u; } v; v.f = f;
  unsigned r = v.u + 0x7fffu + ((v.u >> 16) & 1u);
  return (short)(r >> 16);
}

__device__ __forceinline__ void gload16(const void* g, void* l) {
  __builtin_amdgcn_global_load_lds(
      (const __attribute__((address_space(1))) unsigned int*)g,
      (__attribute__((address_space(3))) unsigned int*)l, 16, 0, 0);
}

__device__ __forceinline__ s8v pack8(float4 a, float4 b) {
  s8v p;
  p[0] = f2bf(a.x); p[1] = f2bf(a.y); p[2] = f2bf(a.z); p[3] = f2bf(a.w);
  p[4] = f2bf(b.x); p[5] = f2bf(b.y); p[6] = f2bf(b.z); p[7] = f2bf(b.w);
  return p;
}

__device__ __forceinline__ bfrag cvt8(f32x4 lo, f32x4 hi) {
  bfrag r;
  r[0] = (__bf16)lo[0]; r[1] = (__bf16)lo[1];
  r[2] = (__bf16)lo[2]; r[3] = (__bf16)lo[3];
  r[4] = (__bf16)hi[0]; r[5] = (__bf16)hi[1];
  r[6] = (__bf16)hi[2]; r[7] = (__bf16)hi[3];
  return r;
}

// Fused: blocks 0..63 scatter tokens by expert; blocks 64..1087 convert
// weight fp32 -> bf16 (contiguous [E][O][I]). Cursor pre-zeroed by memset.
__global__ void k_prep(const int* __restrict__ gate, int* __restrict__ cursor,
                       int* __restrict__ perm, const float* __restrict__ w,
                       s8v* __restrict__ wb) {
  __shared__ int lc[NEXP], lb[NEXP];
  const int bid = blockIdx.x, tid = threadIdx.x;
  if (bid < 64) {
    if (tid < NEXP) lc[tid] = 0;
    __syncthreads();
    int t = bid * 256 + tid;
    int e = gate[t];
    int ls = atomicAdd(&lc[e], 1);
    __syncthreads();
    if (tid < NEXP) lb[tid] = lc[tid] ? atomicAdd(&cursor[tid], lc[tid]) : 0;
    __syncthreads();
    perm[e * EROWS + lb[e] + ls] = t;
  } else {
    int idx = (bid - 64) * 256 + tid;
    const float4* src = (const float4*)w + (size_t)idx * 2;
    wb[idx] = pack8(src[0], src[1]);
  }
}

#define KBAR(N)                                                         \
  asm volatile("s_waitcnt vmcnt(" #N ") lgkmcnt(0)" ::: "memory");      \
  __builtin_amdgcn_sched_barrier(0);                                    \
  __builtin_amdgcn_s_barrier();                                         \
  __builtin_amdgcn_sched_barrier(0);

// Grouped GEMM = R8-proven homogeneous ring-3 counted-vmcnt pipeline at
// R11-proven geometry/affinity. BM=64 BN=128 BK=32; slot = A 8KB fp32 +
// B 8KB bf16; ring-3 = 48KB -> 3 blocks/CU, 12 waves/CU.
// Per step t: DMA(t+2) [4 gload16]; COMP(t) [8 MFMA]; KBAR(4) retires
// DMA(t+1) with ~2 COMPs of slack; DMA(t+2) rides across the barrier.
// Slot-reuse safety: DMA(t+2) writes slot (t+2)%3, last read at COMP(t-1),
// ordered by step-(t-1)'s KBAR (lgkmcnt(0) + s_barrier).  [R8 template]
// bid = e + 8*(nt + 4*mt): e -> XCD (B_e 524KB L2-hot); 4 nt-siblings of an
// A-tile dispatch back-to-back on the same XCD (A read ~once from HBM).
__global__ __launch_bounds__(256, 3)
void moe_gemm8(const float* __restrict__ inp, const short* __restrict__ wbf,
               const int* __restrict__ cursor, const int* __restrict__ perm,
               float* __restrict__ out) {
  const int bid = blockIdx.x;
  const int e  = bid & 7;
  const int nt = (bid >> 3) & 3;
  const int mt = bid >> 5;
  const int cnt = cursor[e];
  if (mt * BM >= cnt) return;
  const int m_valid = min(BM, cnt - mt * BM);
  const int* pb = perm + e * EROWS + mt * BM;

  __shared__ __align__(16) char Albs[3][BM * BK * 4];   // 3 x 8 KB
  __shared__ __align__(16) char Blbs[3][BN * BK * 2];   // 3 x 8 KB
  __shared__ int toks[BM];

  const int tid = threadIdx.x;
  if (tid < BM) toks[tid] = pb[(tid < m_valid) ? tid : 0];
  __syncthreads();

  const int lane = tid & 63;
  const int wid  = tid >> 6;
  const int wr = wid >> 1, wc = wid & 1;   // wave: rows wr*32..+31, cols wc*64..+63
  const int lr = lane & 15;
  const int lg = lane >> 4;

  // ---- A DMA geometry (R8-proven pattern): 2 sites; chunk = s*256+tid ->
  //      row = s*32+(tid>>3), cphys = tid&7; source clog = cphys^(row&7).
  const float* agp[2];
#pragma unroll
  for (int s = 0; s < 2; s++) {
    int row  = s * 32 + (tid >> 3);
    int clog = (tid & 7) ^ (row & 7);
    agp[s] = inp + (size_t)toks[row] * INF + clog * 4;
  }

  // ---- B DMA geometry: 2 sites; chunk = s*256+tid -> row = s*64+(tid>>2),
  //      cphys = tid&3; source clog = cphys^(row&3).
  const short* Wbase = wbf + ((size_t)e * OUTF + (size_t)nt * BN) * INF;
  const short* bgp[2];
#pragma unroll
  for (int s = 0; s < 2; s++) {
    int row  = s * 64 + (tid >> 2);
    int clog = (tid & 3) ^ (row & 3);
    bgp[s] = Wbase + (size_t)row * INF + clog * 8;
  }

  f32x4 acc[2][4];
#pragma unroll
  for (int m = 0; m < 2; m++)
#pragma unroll
    for (int j = 0; j < 4; j++) acc[m][j] = (f32x4)0.0f;

#define DMA(t_)                                                               \
  {                                                                           \
    char* ab_ = (char*)Albs[(t_) % 3];                                        \
    char* bb_ = (char*)Blbs[(t_) % 3];                                        \
    gload16(agp[0] + (t_) * BK, ab_ + tid * 16);                              \
    gload16(agp[1] + (t_) * BK, ab_ + 4096 + tid * 16);                       \
    gload16(bgp[0] + (t_) * BK, bb_ + tid * 16);                              \
    gload16(bgp[1] + (t_) * BK, bb_ + 4096 + tid * 16);                       \
  }
#define COMP(t_)                                                              \
  {                                                                           \
    const char* ab_ = (const char*)Albs[(t_) % 3];                            \
    const char* bb_ = (const char*)Blbs[(t_) % 3];                            \
    bfrag af[2], bv[4];                                                       \
    _Pragma("unroll") for (int m = 0; m < 2; m++) {                           \
      int row = wr * 32 + m * 16 + lr;                                        \
      int c0 = (lg * 2) ^ (row & 7), c1 = (lg * 2 + 1) ^ (row & 7);           \
      f32x4 lo = *(const f32x4*)(ab_ + row * 128 + c0 * 16);                  \
      f32x4 hi = *(const f32x4*)(ab_ + row * 128 + c1 * 16);                  \
      af[m] = cvt8(lo, hi);                                                   \
    }                                                                         \
    _Pragma("unroll") for (int j = 0; j < 4; j++) {                           \
      int row = wc * 64 + j * 16 + lr;                                        \
      int c = lg ^ (row & 3);                                                 \
      bv[j] = *(const bfrag*)(bb_ + row * 64 + c * 16);                       \
    }                                                                         \
    _Pragma("unroll") for (int m = 0; m < 2; m++)                             \
      _Pragma("unroll") for (int j = 0; j < 4; j++)                           \
          acc[m][j] = __builtin_amdgcn_mfma_f32_16x16x32_bf16(                \
              af[m], bv[j], acc[m][j], 0, 0, 0);                              \
  }

  // ---- prologue: slots 0,1 in flight; retire slot 0 (R8 pattern) ----
  DMA(0);
  DMA(1);
  KBAR(4)

#pragma unroll
  for (int t = 0; t < NST; t++) {
    if (t + 2 < NST) DMA(t + 2);   // rides across the barrier
    COMP(t);
    if (t + 2 < NST) {
      KBAR(4)      // retires DMA(t+1); DMA(t+2) stays in flight
    } else if (t + 1 < NST) {
      KBAR(0)      // drain DMA(NST-1)
    }
  }

  // ---- epilogue: C/D col=lane&15, row=(lane>>4)*4+reg (proven) ----
#pragma unroll
  for (int m = 0; m < 2; m++) {
#pragma unroll
    for (int r = 0; r < 4; r++) {
      int rowE = wr * 32 + m * 16 + lg * 4 + r;
      if (rowE < m_valid) {
        float* orow = out + (size_t)toks[rowE] * OUTF + (size_t)nt * BN +
                      (size_t)wc * 64 + lr;
#pragma unroll
        for (int j = 0; j < 4; j++) orow[j * 16] = acc[m][j][r];
      }
    }
  }
#undef DMA
#undef COMP
}

extern "C" void kernel_launch(void* const* d_in, const int* in_sizes, int n_in,
                              void* d_out, int out_size, void* d_ws, size_t ws_size,
                              hipStream_t stream) {
  (void)in_sizes; (void)n_in; (void)out_size; (void)ws_size;
  const float* inp    = (const float*)d_in[0];
  const int*   gate   = (const int*)d_in[1];
  const float* weight = (const float*)d_in[2];
  float* out = (float*)d_out;

  char* ws = (char*)d_ws;
  int*   cursor = (int*)ws;                    // 64 B
  int*   perm   = (int*)(ws + 4096);           // 8*2560*4 = 80 KB
  short* wbf    = (short*)(ws + (1 << 20));    // 4 MB bf16 weight

  hipMemsetAsync(cursor, 0, 64, stream);       // replaces k_zero launch
  k_prep<<<64 + (NEXP * OUTF * INF) / (256 * 8), 256, 0, stream>>>(
      gate, cursor, perm, weight, (s8v*)wbf);
  moe_gemm8<<<NEXP * 4 * MAXMT, 256, 0, stream>>>(inp, wbf, cursor, perm, out);
}